// Round 4
// baseline (659.233 us; speedup 1.0000x reference)
//
#include <hip/hip_runtime.h>

// Monarch block-MLP, fully fused single kernel (round 4).
// Insight: stages 0_1 -> 1_0 chain block-diagonally in s, so the whole op is
// row-local: 16 rows of x -> 16 rows of out inside one workgroup, no
// intermediate global traffic. Per s-slice (16 of 128):
//   A: Y0[r][s][kb]  = x[r,kb*64+m] @ w0t       (MFMA A=w0 rows=s, B=x cols=r)
//   B: TS[r][s][j]   = elu(Y0 @ w1t + b1)       (A=w1 rows=j, B=Y0 cols=r)
//   C: US[j2][r][s]  = TS @ w2t                 (A=w2 rows=j2, B=TS cols=r)
//   D: acc[s'][j']  += US @ w3t  (K=16 via dup-K32 trick, x2 then 0.5 scale)
// Weights pre-transposed+bf16 (4MB, L2-resident). x pre-cast to bf16 scratch
// by the same workgroup (tile-private), re-read 8x from L2.

typedef __attribute__((ext_vector_type(8))) short short8;
typedef __attribute__((ext_vector_type(4))) float floatx4;
typedef unsigned int uint;

#define MFMA32(a, b, c) __builtin_amdgcn_mfma_f32_16x16x32_bf16(a, b, c, 0, 0, 0)

__device__ __forceinline__ unsigned short f2bf(float f) {
    uint u = __float_as_uint(f);
    uint r = 0x7FFFu + ((u >> 16) & 1u);
    return (unsigned short)((u + r) >> 16);
}
__device__ __forceinline__ short8 ld8(const unsigned short* p) {
    return *reinterpret_cast<const short8*>(p);
}

// out[b][c][r] = bf16(in[b][r][c])
__global__ void transpose_cast_k(const float* __restrict__ in,
                                 unsigned short* __restrict__ out,
                                 int Bn, int R, int C) {
    int total = Bn * R * C;
    int stride = gridDim.x * blockDim.x;
    for (int idx = blockIdx.x * blockDim.x + threadIdx.x; idx < total; idx += stride) {
        int rc = R * C;
        int b = idx / rc;
        int rem = idx - b * rc;
        int c = rem / R;
        int r = rem - c * R;
        out[idx] = f2bf(in[(size_t)(b * R + r) * C + c]);
    }
}

// MFMA 16x16x32 bf16 layouts (m89-verified):
//   A: row = lane&15, k = (lane>>4)*8 + i ;  B: col = lane&15, same k
//   D: col(=B col) = lane&15, row(=A row) = (lane>>4)*4 + reg
__global__ __launch_bounds__(512, 2) void monarch_fused(
    const float* __restrict__ x,             // [bs][4096] f32
    const unsigned short* __restrict__ w0t,  // [kb64][s128][m64]
    const unsigned short* __restrict__ w1t,  // [s128][j64][kb64]
    const unsigned short* __restrict__ w2t,  // [s128][j2 64][j64]
    const unsigned short* __restrict__ w3t,  // [s'64][j'64][s128]
    const float* __restrict__ b1,            // [8192]
    const float* __restrict__ b3,            // [4096]
    unsigned short* __restrict__ xbt,        // [bs][4096] bf16 scratch
    float* __restrict__ out)                 // [bs][4096] f32
{
    const int tid  = threadIdx.x;
    const int lane = tid & 63;
    const int wv   = tid >> 6;     // 0..7
    const int l15  = lane & 15;
    const int l4   = lane >> 4;    // 0..3
    const int r0   = blockIdx.x * 16;

    // sh1 aliases Y0 (A->B) and US (C->D); TS separate. 91 KB total.
    __shared__ __align__(16) unsigned short sh1[64 * 17 * 24];
    __shared__ __align__(16) unsigned short tsb[16 * 17 * 72];
#define Y0(r, s, kb)  sh1[((r) * 17 + (s)) * 72 + (kb)]
#define USs(sp, r, s) sh1[((sp) * 17 + (r)) * 24 + (s)]
#define TS(r, s, j)   tsb[((r) * 17 + (s)) * 72 + (j)]

    // ---- phase 0: cast this tile's 16 rows f32 -> bf16 scratch ----
#pragma unroll
    for (int i = 0; i < 2; ++i) {
        const int row = r0 + wv * 2 + i;
        const float* xr = x + (size_t)row * 4096;
        unsigned short* xo = xbt + (size_t)row * 4096;
#pragma unroll
        for (int c = 0; c < 8; ++c) {
            const int cc = c * 512 + lane * 8;
            floatx4 f0 = *reinterpret_cast<const floatx4*>(xr + cc);
            floatx4 f1 = *reinterpret_cast<const floatx4*>(xr + cc + 4);
            short8 o;
#pragma unroll
            for (int j = 0; j < 4; ++j) {
                o[j]     = (short)f2bf(f0[j]);
                o[j + 4] = (short)f2bf(f1[j]);
            }
            *reinterpret_cast<short8*>(xo + cc) = o;
        }
    }
    __syncthreads();

    floatx4 accD[8][4];
#pragma unroll
    for (int a = 0; a < 8; ++a)
#pragma unroll
        for (int b = 0; b < 4; ++b) accD[a][b] = (floatx4){0.f, 0.f, 0.f, 0.f};

    const unsigned short* xrow = xbt + (size_t)(r0 + l15) * 4096;

    for (int ss = 0; ss < 8; ++ss) {
        // ---- A: Y0[r][s_local][kb] for s_local 0..15, kb 0..63 ----
#pragma unroll
        for (int t = 0; t < 8; t += 2) {
            const int kb0 = wv * 8 + t;
            floatx4 d0, d1;
            {
                const unsigned short* xp = xrow + kb0 * 64 + l4 * 8;
                const unsigned short* wp =
                    w0t + ((size_t)kb0 * 128 + ss * 16 + l15) * 64 + l4 * 8;
                floatx4 a = (floatx4){0.f, 0.f, 0.f, 0.f};
                a = MFMA32(ld8(wp), ld8(xp), a);
                a = MFMA32(ld8(wp + 32), ld8(xp + 32), a);
                d0 = a;
            }
            {
                const unsigned short* xp = xrow + (kb0 + 1) * 64 + l4 * 8;
                const unsigned short* wp =
                    w0t + ((size_t)(kb0 + 1) * 128 + ss * 16 + l15) * 64 + l4 * 8;
                floatx4 a = (floatx4){0.f, 0.f, 0.f, 0.f};
                a = MFMA32(ld8(wp), ld8(xp), a);
                a = MFMA32(ld8(wp + 32), ld8(xp + 32), a);
                d1 = a;
            }
#pragma unroll
            for (int rg = 0; rg < 4; ++rg) {
                uint pk = (uint)f2bf(d0[rg]) | ((uint)f2bf(d1[rg]) << 16);
                *reinterpret_cast<uint*>(&Y0(l15, l4 * 4 + rg, kb0)) = pk;
            }
        }
        __syncthreads();

        // ---- B: TS[r][s][j] = elu(Y0 @ w1 + b1) ----
#pragma unroll
        for (int sl = 0; sl < 2; ++sl) {
            const int s  = wv * 2 + sl;
            const int sg = ss * 16 + s;
            short8 ya = ld8(&Y0(l15, s, l4 * 8));
            short8 yb = ld8(&Y0(l15, s, 32 + l4 * 8));
#pragma unroll
            for (int jt = 0; jt < 4; ++jt) {
                const unsigned short* wp =
                    w1t + ((size_t)sg * 64 + jt * 16 + l15) * 64 + l4 * 8;
                floatx4 tacc = (floatx4){0.f, 0.f, 0.f, 0.f};
                tacc = MFMA32(ld8(wp), ya, tacc);
                tacc = MFMA32(ld8(wp + 32), yb, tacc);
                const floatx4 bv = *reinterpret_cast<const floatx4*>(
                    b1 + (size_t)sg * 64 + jt * 16 + l4 * 4);
                unsigned long long pk = 0;
#pragma unroll
                for (int rg = 0; rg < 4; ++rg) {
                    float v = tacc[rg] + bv[rg];
                    v = v > 0.f ? v : (__expf(v) - 1.f);
                    pk |= (unsigned long long)f2bf(v) << (16 * rg);
                }
                *reinterpret_cast<unsigned long long*>(
                    &TS(l15, s, jt * 16 + l4 * 4)) = pk;
            }
        }
        __syncthreads();

        // ---- C: US[j2][r][s] = TS @ w2 ----
#pragma unroll
        for (int sl = 0; sl < 2; ++sl) {
            const int s  = wv * 2 + sl;
            const int sg = ss * 16 + s;
            short8 ta = ld8(&TS(l15, s, l4 * 8));
            short8 tb = ld8(&TS(l15, s, 32 + l4 * 8));
#pragma unroll
            for (int jt2 = 0; jt2 < 4; ++jt2) {
                const unsigned short* wp =
                    w2t + ((size_t)sg * 64 + jt2 * 16 + l15) * 64 + l4 * 8;
                floatx4 u = (floatx4){0.f, 0.f, 0.f, 0.f};
                u = MFMA32(ld8(wp), ta, u);
                u = MFMA32(ld8(wp + 32), tb, u);
#pragma unroll
                for (int rg = 0; rg < 4; ++rg)
                    USs(jt2 * 16 + l4 * 4 + rg, l15, s) = f2bf(u[rg]);
            }
        }
        __syncthreads();

        // ---- D: accD += US @ w3 (K=16 duplicated into K=32 -> 2x result) ----
#pragma unroll
        for (int sp = 0; sp < 8; ++sp) {
            const int spp = wv * 8 + sp;
            short8 uf = ld8(&USs(spp, l15, (l4 & 1) * 8));
#pragma unroll
            for (int jt = 0; jt < 4; ++jt) {
                const unsigned short* wp =
                    w3t + ((size_t)spp * 64 + jt * 16 + l15) * 128 + ss * 16 + (l4 & 1) * 8;
                accD[sp][jt] = MFMA32(ld8(wp), uf, accD[sp][jt]);
            }
        }
        __syncthreads();   // US (aliased with Y0) must be fully read before next A
    }

    // ---- epilogue: out = 0.5*accD + b3 (dwordx4 stores) ----
#pragma unroll
    for (int sp = 0; sp < 8; ++sp) {
        const int spp = wv * 8 + sp;
#pragma unroll
        for (int jt = 0; jt < 4; ++jt) {
            const floatx4 bv = *reinterpret_cast<const floatx4*>(
                b3 + spp * 64 + jt * 16 + l4 * 4);
            floatx4 r;
#pragma unroll
            for (int rg = 0; rg < 4; ++rg) r[rg] = 0.5f * accD[sp][jt][rg] + bv[rg];
            *reinterpret_cast<floatx4*>(
                out + (size_t)(r0 + l15) * 4096 + spp * 64 + jt * 16 + l4 * 4) = r;
        }
    }
#undef Y0
#undef USs
#undef TS
}

extern "C" void kernel_launch(void* const* d_in, const int* in_sizes, int n_in,
                              void* d_out, int out_size, void* d_ws, size_t ws_size,
                              hipStream_t stream) {
    const float* x  = (const float*)d_in[0];
    const float* w0 = (const float*)d_in[1];
    const float* w1 = (const float*)d_in[2];
    const float* b1 = (const float*)d_in[3];
    const float* w2 = (const float*)d_in[4];
    const float* w3 = (const float*)d_in[5];
    const float* b3 = (const float*)d_in[6];
    float* out = (float*)d_out;

    const int bs = in_sizes[0] / 4096;

    // ws (u16): w0t | w1t | w2t | w3t (512K elems each) | xbt [bs*4096]
    unsigned short* w0t = (unsigned short*)d_ws;
    unsigned short* w1t = w0t + 64 * 128 * 64;
    unsigned short* w2t = w1t + 128 * 64 * 64;
    unsigned short* w3t = w2t + 128 * 64 * 64;
    unsigned short* xbt = w3t + 64 * 64 * 128;
    const size_t need = (4ull * 524288 + (size_t)bs * 4096) * sizeof(unsigned short);
    if (n_in < 7 || (bs & 15) || ws_size < need) return;

    transpose_cast_k<<<dim3(512), dim3(256), 0, stream>>>(w0, w0t, 64, 64, 128);
    transpose_cast_k<<<dim3(512), dim3(256), 0, stream>>>(w1, w1t, 128, 64, 64);
    transpose_cast_k<<<dim3(512), dim3(256), 0, stream>>>(w2, w2t, 128, 64, 64);
    transpose_cast_k<<<dim3(512), dim3(256), 0, stream>>>(w3, w3t, 64, 128, 64);

    monarch_fused<<<dim3(bs / 16), dim3(512), 0, stream>>>(
        x, w0t, w1t, w2t, w3t, b1, b3, xbt, out);
}

// Round 5
// 579.793 us; speedup vs baseline: 1.1370x; 1.1370x over previous
//
#include <hip/hip_runtime.h>

// Monarch block-MLP, round 5: two fused kernels (A+B -> z, C+D -> out),
// fat phases (32 MFMA/wave between barriers), explicit 2-tile register
// prefetch, XOR-swizzled y0 LDS (T2), 2 wg/CU (VGPR<=128, LDS 78KB).

typedef __attribute__((ext_vector_type(8))) short short8;
typedef __attribute__((ext_vector_type(4))) float floatx4;
typedef unsigned int uint;

#define MFMA32(a, b, c) __builtin_amdgcn_mfma_f32_16x16x32_bf16(a, b, c, 0, 0, 0)

__device__ __forceinline__ unsigned short f2bf(float f) {
    uint u = __float_as_uint(f);
    uint r = 0x7FFFu + ((u >> 16) & 1u);
    return (unsigned short)((u + r) >> 16);
}
__device__ __forceinline__ short8 ld8(const unsigned short* p) {
    return *reinterpret_cast<const short8*>(p);
}

struct Frag { short8 a0, a1, b0, b1; };

__global__ void cast_x_bf16(const float* __restrict__ in,
                            unsigned short* __restrict__ out, int n8) {
    int stride = gridDim.x * blockDim.x;
    for (int idx = blockIdx.x * blockDim.x + threadIdx.x; idx < n8; idx += stride) {
        const float* p = in + (size_t)idx * 8;
        floatx4 f0 = *reinterpret_cast<const floatx4*>(p);
        floatx4 f1 = *reinterpret_cast<const floatx4*>(p + 4);
        short8 o;
#pragma unroll
        for (int j = 0; j < 4; ++j) {
            o[j]     = (short)f2bf(f0[j]);
            o[j + 4] = (short)f2bf(f1[j]);
        }
        *reinterpret_cast<short8*>(out + (size_t)idx * 8) = o;
    }
}

// out[b][c][r] = bf16(in[b][r][c])
__global__ void transpose_cast_k(const float* __restrict__ in,
                                 unsigned short* __restrict__ out,
                                 int Bn, int R, int C) {
    int total = Bn * R * C;
    int stride = gridDim.x * blockDim.x;
    for (int idx = blockIdx.x * blockDim.x + threadIdx.x; idx < total; idx += stride) {
        int rc = R * C;
        int b = idx / rc;
        int rem = idx - b * rc;
        int c = rem / R;
        int r = rem - c * R;
        out[idx] = f2bf(in[(size_t)(b * R + r) * C + c]);
    }
}

// MFMA 16x16x32 bf16 layouts (m89-verified):
//   A: row = lane&15, k = (lane>>4)*8 + i ;  B: col = lane&15, same k
//   D: col = lane&15, row = (lane>>4)*4 + reg
template<int KB, int SN, bool ELU>
__global__ __launch_bounds__(512, 4) void fusedR5(
    const unsigned short* __restrict__ xb,    // [bs][KB*64] bf16
    const unsigned short* __restrict__ wat,   // [KB][SN][64] bf16
    const unsigned short* __restrict__ wbt,   // [SN][64][KB] bf16
    const float* __restrict__ bias,           // [SN*64]
    unsigned short* __restrict__ ob,          // bf16 out (ELU)
    float* __restrict__ of)                   // f32 out
{
    constexpr int G  = KB / 64;
    constexpr int IW = KB * 64;
    constexpr int OW = SN * 64;

    const int tid  = threadIdx.x;
    const int lane = tid & 63;
    const int wv   = tid >> 6;       // 0..7
    const int l15  = lane & 15;
    const int l4   = lane >> 4;      // 0..3
    const int rt   = wv >> 2;        // row half
    const int wq   = wv & 3;         // kb stripe (A) / j quarter (B)
    const int r0   = blockIdx.x * 32;
    const int s0   = blockIdx.y * 16;

    // y0[r(32)][s(17)][k(72)] bf16, 78336 B; XOR swizzle byte^=(r&7)<<4 on
    // both sides fixes the 8-way b128 read conflict (pads alone cannot).
    __shared__ __align__(16) unsigned short y0s[32 * 17 * 72];
    char* yb = (char*)y0s;
    auto yoff = [&](int r, int s, int k) -> int {
        return (((r * 17 + s) * 72 + k) * 2) ^ ((r & 7) << 4);
    };

    floatx4 acc[16];
#pragma unroll
    for (int s = 0; s < 16; ++s) acc[s] = (floatx4){0.f, 0.f, 0.f, 0.f};

    const unsigned short* xrow = xb + (size_t)(r0 + rt * 16 + l15) * IW;

    for (int g = 0; g < G; ++g) {
        const int kbase = g * 64 + wq * 16;   // wave's 16 kb within group

        auto ldT = [&](int t) -> Frag {
            Frag f;
            const unsigned short* xp = xrow + (kbase + t) * 64 + l4 * 8;
            const unsigned short* wp =
                wat + ((size_t)(kbase + t) * SN + s0 + l15) * 64 + l4 * 8;
            f.a0 = ld8(xp);      f.a1 = ld8(xp + 32);
            f.b0 = ld8(wp);      f.b1 = ld8(wp + 32);
            return f;
        };

        // ---- stage A: 16 tiles, 2-tile-ahead register prefetch ----
        Frag f0 = ldT(0), f1 = ldT(1);
        floatx4 dprev;
#pragma unroll
        for (int t = 0; t < 16; ++t) {
            Frag fn = (t < 14) ? ldT(t + 2) : f1;
            floatx4 d = (floatx4){0.f, 0.f, 0.f, 0.f};
            d = MFMA32(f0.a0, f0.b0, d);
            d = MFMA32(f0.a1, f0.b1, d);
            if (t & 1) {
                const int kbl = wq * 16 + t - 1;   // even
#pragma unroll
                for (int rg = 0; rg < 4; ++rg) {
                    uint pk = (uint)f2bf(dprev[rg]) | ((uint)f2bf(d[rg]) << 16);
                    *reinterpret_cast<uint*>(
                        yb + yoff(rt * 16 + l4 * 4 + rg, l15, kbl)) = pk;
                }
            } else {
                dprev = d;
            }
            f0 = f1; f1 = fn;
        }
        __syncthreads();

        // ---- stage B: 16 s, K=64 (2 MFMA each), next-frag prefetch ----
        auto wb = [&](int s) -> const unsigned short* {
            return wbt + ((size_t)(s0 + s) * 64 + wq * 16 + l15) * KB + g * 64 + l4 * 8;
        };
        short8 nb0 = ld8(wb(0)), nb1 = ld8(wb(0) + 32);
#pragma unroll
        for (int s = 0; s < 16; ++s) {
            short8 b0 = nb0, b1 = nb1;
            if (s < 15) { nb0 = ld8(wb(s + 1)); nb1 = ld8(wb(s + 1) + 32); }
            short8 af0 = *reinterpret_cast<const short8*>(
                yb + yoff(rt * 16 + l15, s, l4 * 8));
            short8 af1 = *reinterpret_cast<const short8*>(
                yb + yoff(rt * 16 + l15, s, 32 + l4 * 8));
            acc[s] = MFMA32(af0, b0, acc[s]);
            acc[s] = MFMA32(af1, b1, acc[s]);
        }
        if (g + 1 < G) __syncthreads();
    }

    // ---- epilogue ----
#pragma unroll
    for (int s = 0; s < 16; ++s) {
        const int col = (s0 + s) * 64 + wq * 16 + l15;
        const float bv = bias[col];
#pragma unroll
        for (int rg = 0; rg < 4; ++rg) {
            const int row = r0 + rt * 16 + l4 * 4 + rg;
            float v = acc[s][rg] + bv;
            if constexpr (ELU) {
                v = v > 0.f ? v : (__expf(v) - 1.f);
                ob[(size_t)row * OW + col] = f2bf(v);
            } else {
                of[(size_t)row * OW + col] = v;
            }
        }
    }
}

extern "C" void kernel_launch(void* const* d_in, const int* in_sizes, int n_in,
                              void* d_out, int out_size, void* d_ws, size_t ws_size,
                              hipStream_t stream) {
    const float* x  = (const float*)d_in[0];
    const float* w0 = (const float*)d_in[1];
    const float* w1 = (const float*)d_in[2];
    const float* b1 = (const float*)d_in[3];
    const float* w2 = (const float*)d_in[4];
    const float* w3 = (const float*)d_in[5];
    const float* b3 = (const float*)d_in[6];
    float* out = (float*)d_out;

    const int bs = in_sizes[0] / 4096;

    // ws (u16): z[bs*8192] | w0t | w1t | w2t | w3t | xb[bs*4096]
    unsigned short* z   = (unsigned short*)d_ws;
    const size_t zElems = (size_t)bs * 8192;
    unsigned short* w0t = z + zElems;
    unsigned short* w1t = w0t + 64 * 128 * 64;
    unsigned short* w2t = w1t + 128 * 64 * 64;
    unsigned short* w3t = w2t + 128 * 64 * 64;
    unsigned short* xb  = w3t + 64 * 128 * 64;
    const size_t need1 = (zElems + 4ull * 524288) * sizeof(unsigned short);
    const size_t need2 = need1 + (size_t)bs * 4096 * sizeof(unsigned short);
    if (n_in < 7 || (bs & 31) || ws_size < need1) return;
    if (ws_size < need2) xb = (unsigned short*)d_out;  // dead until K2 writes

    transpose_cast_k<<<dim3(512), dim3(256), 0, stream>>>(w0, w0t, 64, 64, 128);
    transpose_cast_k<<<dim3(512), dim3(256), 0, stream>>>(w1, w1t, 128, 64, 64);
    transpose_cast_k<<<dim3(512), dim3(256), 0, stream>>>(w2, w2t, 128, 64, 64);
    transpose_cast_k<<<dim3(512), dim3(256), 0, stream>>>(w3, w3t, 64, 128, 64);
    cast_x_bf16<<<dim3(2048), dim3(256), 0, stream>>>(x, xb, bs * 4096 / 8);

    fusedR5<64, 128, true><<<dim3(bs / 32, 8), dim3(512), 0, stream>>>(
        xb, w0t, w1t, b1, z, nullptr);
    fusedR5<128, 64, false><<<dim3(bs / 32, 4), dim3(512), 0, stream>>>(
        z, w2t, w3t, b3, nullptr, out);
}

// Round 6
// 556.353 us; speedup vs baseline: 1.1849x; 1.0421x over previous
//
#include <hip/hip_runtime.h>

// Monarch block-MLP, round 6: R5 fat-phase structure + bijective XCD-chunked
// blockIdx remap (8 rowtiles x all stiles per chunk -> streamed-operand
// re-reads become same-XCD L2 hits) + depth-3 register prefetch in stage A.

typedef __attribute__((ext_vector_type(8))) short short8;
typedef __attribute__((ext_vector_type(4))) float floatx4;
typedef unsigned int uint;

#define MFMA32(a, b, c) __builtin_amdgcn_mfma_f32_16x16x32_bf16(a, b, c, 0, 0, 0)

__device__ __forceinline__ unsigned short f2bf(float f) {
    uint u = __float_as_uint(f);
    uint r = 0x7FFFu + ((u >> 16) & 1u);
    return (unsigned short)((u + r) >> 16);
}
__device__ __forceinline__ short8 ld8(const unsigned short* p) {
    return *reinterpret_cast<const short8*>(p);
}

struct Frag { short8 a0, a1, b0, b1; };

__global__ void cast_x_bf16(const float* __restrict__ in,
                            unsigned short* __restrict__ out, int n8) {
    int stride = gridDim.x * blockDim.x;
    for (int idx = blockIdx.x * blockDim.x + threadIdx.x; idx < n8; idx += stride) {
        const float* p = in + (size_t)idx * 8;
        floatx4 f0 = *reinterpret_cast<const floatx4*>(p);
        floatx4 f1 = *reinterpret_cast<const floatx4*>(p + 4);
        short8 o;
#pragma unroll
        for (int j = 0; j < 4; ++j) {
            o[j]     = (short)f2bf(f0[j]);
            o[j + 4] = (short)f2bf(f1[j]);
        }
        *reinterpret_cast<short8*>(out + (size_t)idx * 8) = o;
    }
}

// out[b][c][r] = bf16(in[b][r][c])
__global__ void transpose_cast_k(const float* __restrict__ in,
                                 unsigned short* __restrict__ out,
                                 int Bn, int R, int C) {
    int total = Bn * R * C;
    int stride = gridDim.x * blockDim.x;
    for (int idx = blockIdx.x * blockDim.x + threadIdx.x; idx < total; idx += stride) {
        int rc = R * C;
        int b = idx / rc;
        int rem = idx - b * rc;
        int c = rem / R;
        int r = rem - c * R;
        out[idx] = f2bf(in[(size_t)(b * R + r) * C + c]);
    }
}

// MFMA 16x16x32 bf16 layouts (m89-verified):
//   A: row = lane&15, k = (lane>>4)*8 + i ;  B: col = lane&15, same k
//   D: col = lane&15, row = (lane>>4)*4 + reg
template<int KB, int SN, bool ELU>
__global__ __launch_bounds__(512, 4) void fusedR6(
    const unsigned short* __restrict__ xb,    // [bs][KB*64] bf16
    const unsigned short* __restrict__ wat,   // [KB][SN][64] bf16
    const unsigned short* __restrict__ wbt,   // [SN][64][KB] bf16
    const float* __restrict__ bias,           // [SN*64]
    unsigned short* __restrict__ ob,          // bf16 out (ELU)
    float* __restrict__ of)                   // f32 out
{
    constexpr int G   = KB / 64;
    constexpr int IW  = KB * 64;
    constexpr int OW  = SN * 64;
    constexpr int NS  = SN / 16;      // stiles per rowtile (8 or 4)
    constexpr int GSZ = 8 * NS;       // wgs per rowtile-group

    const int tid  = threadIdx.x;
    const int lane = tid & 63;
    const int wv   = tid >> 6;       // 0..7
    const int l15  = lane & 15;
    const int l4   = lane >> 4;      // 0..3
    const int rt   = wv >> 2;        // row half
    const int wq   = wv & 3;         // kb stripe (A) / j quarter (B)

    // ---- XCD-chunked bijective remap (T1 + stile-inner grouping) ----
    // hw wgs round-robin XCDs (hw&7). Give each XCD a contiguous logical
    // chunk ordered as [rowtile-group of 8][stile][rowtile-in-group] so all
    // stiles of 8 rowtiles are co-resident -> streamed re-reads hit L2.
    const int nwg = gridDim.x;
    const int C   = nwg >> 3;
    int rowtile, stile;
    if (((nwg & 7) == 0) && ((C % GSZ) == 0)) {
        const int xcd  = blockIdx.x & 7;
        const int slot = blockIdx.x >> 3;
        const int grp  = slot / GSZ;
        const int rem  = slot - grp * GSZ;
        const int st   = rem >> 3;          // stile
        const int rtl  = rem & 7;           // rowtile within group
        rowtile = xcd * (C / NS) + grp * 8 + rtl;
        stile   = st;
    } else {
        rowtile = blockIdx.x / NS;
        stile   = blockIdx.x - rowtile * NS;
    }
    const int r0 = rowtile * 32;
    const int s0 = stile * 16;

    // y0[r(32)][s(17)][k(72)] bf16, 78336 B; XOR swizzle byte^=(r&7)<<4 on
    // both sides fixes the 8-way b128 read conflict.
    __shared__ __align__(16) unsigned short y0s[32 * 17 * 72];
    char* yb = (char*)y0s;
    auto yoff = [&](int r, int s, int k) -> int {
        return (((r * 17 + s) * 72 + k) * 2) ^ ((r & 7) << 4);
    };

    floatx4 acc[16];
#pragma unroll
    for (int s = 0; s < 16; ++s) acc[s] = (floatx4){0.f, 0.f, 0.f, 0.f};

    const unsigned short* xrow = xb + (size_t)(r0 + rt * 16 + l15) * IW;

    for (int g = 0; g < G; ++g) {
        const int kbase = g * 64 + wq * 16;   // wave's 16 kb within group

        auto ldT = [&](int t) -> Frag {
            Frag f;
            const unsigned short* xp = xrow + (kbase + t) * 64 + l4 * 8;
            const unsigned short* wp =
                wat + ((size_t)(kbase + t) * SN + s0 + l15) * 64 + l4 * 8;
            f.a0 = ld8(xp);      f.a1 = ld8(xp + 32);
            f.b0 = ld8(wp);      f.b1 = ld8(wp + 32);
            return f;
        };

        // ---- stage A: 16 tiles, 3-tile-ahead register prefetch ----
        Frag f0 = ldT(0), f1 = ldT(1), f2 = ldT(2);
        floatx4 dprev;
#pragma unroll
        for (int t = 0; t < 16; ++t) {
            Frag fn = (t < 13) ? ldT(t + 3) : f2;
            floatx4 d = (floatx4){0.f, 0.f, 0.f, 0.f};
            d = MFMA32(f0.a0, f0.b0, d);
            d = MFMA32(f0.a1, f0.b1, d);
            if (t & 1) {
                const int kbl = wq * 16 + t - 1;   // even
#pragma unroll
                for (int rg = 0; rg < 4; ++rg) {
                    uint pk = (uint)f2bf(dprev[rg]) | ((uint)f2bf(d[rg]) << 16);
                    *reinterpret_cast<uint*>(
                        yb + yoff(rt * 16 + l4 * 4 + rg, l15, kbl)) = pk;
                }
            } else {
                dprev = d;
            }
            f0 = f1; f1 = f2; f2 = fn;
        }
        __syncthreads();

        // ---- stage B: 16 s, K=64 (2 MFMA each), next-frag prefetch ----
        auto wb = [&](int s) -> const unsigned short* {
            return wbt + ((size_t)(s0 + s) * 64 + wq * 16 + l15) * KB + g * 64 + l4 * 8;
        };
        short8 nb0 = ld8(wb(0)), nb1 = ld8(wb(0) + 32);
#pragma unroll
        for (int s = 0; s < 16; ++s) {
            short8 b0 = nb0, b1 = nb1;
            if (s < 15) { nb0 = ld8(wb(s + 1)); nb1 = ld8(wb(s + 1) + 32); }
            short8 af0 = *reinterpret_cast<const short8*>(
                yb + yoff(rt * 16 + l15, s, l4 * 8));
            short8 af1 = *reinterpret_cast<const short8*>(
                yb + yoff(rt * 16 + l15, s, 32 + l4 * 8));
            acc[s] = MFMA32(af0, b0, acc[s]);
            acc[s] = MFMA32(af1, b1, acc[s]);
        }
        if (g + 1 < G) __syncthreads();
    }

    // ---- epilogue ----
#pragma unroll
    for (int s = 0; s < 16; ++s) {
        const int col = (s0 + s) * 64 + wq * 16 + l15;
        const float bv = bias[col];
#pragma unroll
        for (int rg = 0; rg < 4; ++rg) {
            const int row = r0 + rt * 16 + l4 * 4 + rg;
            float v = acc[s][rg] + bv;
            if constexpr (ELU) {
                v = v > 0.f ? v : (__expf(v) - 1.f);
                ob[(size_t)row * OW + col] = f2bf(v);
            } else {
                of[(size_t)row * OW + col] = v;
            }
        }
    }
}

extern "C" void kernel_launch(void* const* d_in, const int* in_sizes, int n_in,
                              void* d_out, int out_size, void* d_ws, size_t ws_size,
                              hipStream_t stream) {
    const float* x  = (const float*)d_in[0];
    const float* w0 = (const float*)d_in[1];
    const float* w1 = (const float*)d_in[2];
    const float* b1 = (const float*)d_in[3];
    const float* w2 = (const float*)d_in[4];
    const float* w3 = (const float*)d_in[5];
    const float* b3 = (const float*)d_in[6];
    float* out = (float*)d_out;

    const int bs = in_sizes[0] / 4096;

    // ws (u16): z[bs*8192] | w0t | w1t | w2t | w3t | xb[bs*4096]
    unsigned short* z   = (unsigned short*)d_ws;
    const size_t zElems = (size_t)bs * 8192;
    unsigned short* w0t = z + zElems;
    unsigned short* w1t = w0t + 64 * 128 * 64;
    unsigned short* w2t = w1t + 128 * 64 * 64;
    unsigned short* w3t = w2t + 128 * 64 * 64;
    unsigned short* xb  = w3t + 64 * 128 * 64;
    const size_t need1 = (zElems + 4ull * 524288) * sizeof(unsigned short);
    const size_t need2 = need1 + (size_t)bs * 4096 * sizeof(unsigned short);
    if (n_in < 7 || (bs & 31) || ws_size < need1) return;
    if (ws_size < need2) xb = (unsigned short*)d_out;  // dead until K2 writes

    transpose_cast_k<<<dim3(512), dim3(256), 0, stream>>>(w0, w0t, 64, 64, 128);
    transpose_cast_k<<<dim3(512), dim3(256), 0, stream>>>(w1, w1t, 128, 64, 64);
    transpose_cast_k<<<dim3(512), dim3(256), 0, stream>>>(w2, w2t, 128, 64, 64);
    transpose_cast_k<<<dim3(512), dim3(256), 0, stream>>>(w3, w3t, 64, 128, 64);
    cast_x_bf16<<<dim3(2048), dim3(256), 0, stream>>>(x, xb, bs * 4096 / 8);

    fusedR6<64, 128, true><<<dim3((bs / 32) * 8), dim3(512), 0, stream>>>(
        xb, w0t, w1t, b1, z, nullptr);
    fusedR6<128, 64, false><<<dim3((bs / 32) * 4), dim3(512), 0, stream>>>(
        z, w2t, w3t, b3, nullptr, out);
}

// Round 7
// 526.959 us; speedup vs baseline: 1.2510x; 1.0558x over previous
//
#include <hip/hip_runtime.h>

// Monarch block-MLP, round 7: latency-hiding rebuild.
// 256-thr wgs (4 waves), 16r x 16s tile, launch_bounds(256,3) -> ~170 regs:
// depth-4 static Frag pipeline in stage A, depth-2 weight prefetch in stage B,
// 32-kb groups (21.8KB LDS), XCD-chunked remap, LDS-staged coalesced epilogue.

typedef __attribute__((ext_vector_type(8))) short short8;
typedef __attribute__((ext_vector_type(4))) float floatx4;
typedef unsigned int uint;

#define MFMA32(a, b, c) __builtin_amdgcn_mfma_f32_16x16x32_bf16(a, b, c, 0, 0, 0)

__device__ __forceinline__ unsigned short f2bf(float f) {
    uint u = __float_as_uint(f);
    uint r = 0x7FFFu + ((u >> 16) & 1u);
    return (unsigned short)((u + r) >> 16);
}
__device__ __forceinline__ short8 ld8(const unsigned short* p) {
    return *reinterpret_cast<const short8*>(p);
}

struct Frag { short8 a0, a1, b0, b1; };

__global__ void cast_x_bf16(const float* __restrict__ in,
                            unsigned short* __restrict__ out, int n8) {
    int stride = gridDim.x * blockDim.x;
    for (int idx = blockIdx.x * blockDim.x + threadIdx.x; idx < n8; idx += stride) {
        const float* p = in + (size_t)idx * 8;
        floatx4 f0 = *reinterpret_cast<const floatx4*>(p);
        floatx4 f1 = *reinterpret_cast<const floatx4*>(p + 4);
        short8 o;
#pragma unroll
        for (int j = 0; j < 4; ++j) {
            o[j]     = (short)f2bf(f0[j]);
            o[j + 4] = (short)f2bf(f1[j]);
        }
        *reinterpret_cast<short8*>(out + (size_t)idx * 8) = o;
    }
}

// out[b][c][r] = bf16(in[b][r][c])
__global__ void transpose_cast_k(const float* __restrict__ in,
                                 unsigned short* __restrict__ out,
                                 int Bn, int R, int C) {
    int total = Bn * R * C;
    int stride = gridDim.x * blockDim.x;
    for (int idx = blockIdx.x * blockDim.x + threadIdx.x; idx < total; idx += stride) {
        int rc = R * C;
        int b = idx / rc;
        int rem = idx - b * rc;
        int c = rem / R;
        int r = rem - c * R;
        out[idx] = f2bf(in[(size_t)(b * R + r) * C + c]);
    }
}

// MFMA 16x16x32 bf16 layouts (m89-verified):
//   A: row = lane&15, k = (lane>>4)*8 + i ;  B: col = lane&15, same k
//   D: col = lane&15, row = (lane>>4)*4 + reg
template<int KB, int SN, bool ELU>
__global__ __launch_bounds__(256, 3) void fusedR7(
    const unsigned short* __restrict__ xb,    // [bs][KB*64] bf16
    const unsigned short* __restrict__ wat,   // [KB][SN][64] bf16
    const unsigned short* __restrict__ wbt,   // [SN][64][KB] bf16
    const float* __restrict__ bias,           // [SN*64]
    unsigned short* __restrict__ ob,          // bf16 out (ELU)
    float* __restrict__ of)                   // f32 out
{
    constexpr int G   = KB / 32;      // 32-kb groups
    constexpr int IW  = KB * 64;
    constexpr int OW  = SN * 64;
    constexpr int NS  = SN / 16;      // stiles (8 or 4)
    constexpr int GSZ = 8 * NS;       // wgs per rowtile-group of 8

    const int tid  = threadIdx.x;
    const int lane = tid & 63;
    const int wv   = tid >> 6;        // 0..3
    const int l15  = lane & 15;
    const int l4   = lane >> 4;       // 0..3

    // XCD-chunked bijective remap: 8 rowtiles x all stiles per chunk.
    const int nwg = gridDim.x;
    const int C   = nwg >> 3;
    int rowtile, stile;
    if (((nwg & 7) == 0) && ((C % GSZ) == 0)) {
        const int xcd  = blockIdx.x & 7;
        const int slot = blockIdx.x >> 3;
        const int grp  = slot / GSZ;
        const int rem  = slot - grp * GSZ;
        rowtile = xcd * (C / NS) + grp * 8 + (rem & 7);
        stile   = rem >> 3;
    } else {
        rowtile = blockIdx.x / NS;
        stile   = blockIdx.x - rowtile * NS;
    }
    const int r0 = rowtile * 16;
    const int s0 = stile * 16;

    // y0[r16][s17][k40] bf16 = 21760 B, XOR swizzle byte^=(r&7)<<4.
    // Reused as the epilogue staging buffer (16 KB needed).
    __shared__ __align__(16) unsigned short y0s[16 * 17 * 40];
    char* yb = (char*)y0s;
    auto yoff = [&](int r, int s, int k) -> int {
        return (((r * 17 + s) * 40 + k) * 2) ^ ((r & 7) << 4);
    };

    floatx4 acc[16];
#pragma unroll
    for (int s = 0; s < 16; ++s) acc[s] = (floatx4){0.f, 0.f, 0.f, 0.f};

    const unsigned short* xrow = xb + (size_t)(r0 + l15) * IW;

    for (int g = 0; g < G; ++g) {
        const int kbase = g * 32 + wv * 8;     // wave's 8-kb stripe

        auto ldT = [&](int t) -> Frag {
            Frag f;
            const unsigned short* xp = xrow + (kbase + t) * 64 + l4 * 8;
            const unsigned short* wp =
                wat + ((size_t)(kbase + t) * SN + s0 + l15) * 64 + l4 * 8;
            f.a0 = ld8(xp);  f.a1 = ld8(xp + 32);
            f.b0 = ld8(wp);  f.b1 = ld8(wp + 32);
            return f;
        };

        // ---- stage A: 8 kb tiles, depth-4 static circular pipeline ----
        Frag fr[4];
        fr[0] = ldT(0); fr[1] = ldT(1); fr[2] = ldT(2); fr[3] = ldT(3);
        floatx4 dprev = (floatx4){0.f, 0.f, 0.f, 0.f};
#pragma unroll
        for (int t = 0; t < 8; ++t) {
            Frag cur = fr[t & 3];
            if (t < 4) fr[t & 3] = ldT(t + 4);
            floatx4 d = (floatx4){0.f, 0.f, 0.f, 0.f};
            d = MFMA32(cur.a0, cur.b0, d);
            d = MFMA32(cur.a1, cur.b1, d);
            if (t & 1) {
                const int kbl = wv * 8 + t - 1;   // even k, pack (k, k+1)
#pragma unroll
                for (int rg = 0; rg < 4; ++rg) {
                    uint pk = (uint)f2bf(dprev[rg]) | ((uint)f2bf(d[rg]) << 16);
                    *reinterpret_cast<uint*>(yb + yoff(l4 * 4 + rg, l15, kbl)) = pk;
                }
            } else {
                dprev = d;
            }
        }
        __syncthreads();

        // ---- stage B: 16 s, K=32 (1 MFMA each), depth-2 weight prefetch ----
        auto wb = [&](int s) -> const unsigned short* {
            return wbt + ((size_t)(s0 + s) * 64 + wv * 16 + l15) * KB + g * 32 + l4 * 8;
        };
        short8 nb0 = ld8(wb(0)), nb1 = ld8(wb(1));
#pragma unroll
        for (int s = 0; s < 16; ++s) {
            short8 b = (s & 1) ? nb1 : nb0;
            if (s + 2 < 16) {
                if (s & 1) nb1 = ld8(wb(s + 2));
                else       nb0 = ld8(wb(s + 2));
            }
            short8 af = *reinterpret_cast<const short8*>(yb + yoff(l15, s, l4 * 8));
            acc[s] = MFMA32(af, b, acc[s]);
        }
        __syncthreads();
    }

    // ---- epilogue: LDS-staged, fully coalesced 16B stores ----
    // chunk = 1024 B per row: K1 8 s (bf16), K2 4 s (f32).
    constexpr int NCH = ELU ? 2 : 4;
    constexpr int SPC = 16 / NCH;
    unsigned short* es16 = y0s;
    float* es32 = (float*)y0s;
    const int rr = tid >> 4;          // 0..15
    const int cc = tid & 15;          // 0..15

#pragma unroll
    for (int ch = 0; ch < NCH; ++ch) {
        if (ch) __syncthreads();
#pragma unroll
        for (int si = 0; si < SPC; ++si) {
            const int s = ch * SPC + si;
            const float bv = bias[(s0 + s) * 64 + wv * 16 + l15];
#pragma unroll
            for (int rg = 0; rg < 4; ++rg) {
                float v = acc[s][rg] + bv;
                const int row = l4 * 4 + rg;
                if constexpr (ELU) {
                    v = v > 0.f ? v : (__expf(v) - 1.f);
                    es16[row * 512 + si * 64 + wv * 16 + l15] = f2bf(v);
                } else {
                    es32[row * 256 + si * 64 + wv * 16 + l15] = v;
                }
            }
        }
        __syncthreads();
#pragma unroll
        for (int p = 0; p < 4; ++p) {
            const int off = p * 256 + cc * 16;     // byte offset within row-chunk
            if constexpr (ELU) {
                short8 v = *reinterpret_cast<const short8*>((char*)es16 + rr * 1024 + off);
                *reinterpret_cast<short8*>(
                    (char*)(ob + (size_t)(r0 + rr) * OW + s0 * 64) + ch * 1024 + off) = v;
            } else {
                floatx4 v = *reinterpret_cast<const floatx4*>((char*)es32 + rr * 1024 + off);
                *reinterpret_cast<floatx4*>(
                    (char*)(of + (size_t)(r0 + rr) * OW + s0 * 64) + ch * 1024 + off) = v;
            }
        }
    }
}

extern "C" void kernel_launch(void* const* d_in, const int* in_sizes, int n_in,
                              void* d_out, int out_size, void* d_ws, size_t ws_size,
                              hipStream_t stream) {
    const float* x  = (const float*)d_in[0];
    const float* w0 = (const float*)d_in[1];
    const float* w1 = (const float*)d_in[2];
    const float* b1 = (const float*)d_in[3];
    const float* w2 = (const float*)d_in[4];
    const float* w3 = (const float*)d_in[5];
    const float* b3 = (const float*)d_in[6];
    float* out = (float*)d_out;

    const int bs = in_sizes[0] / 4096;

    // ws (u16): z[bs*8192] | w0t | w1t | w2t | w3t | xb[bs*4096]
    unsigned short* z   = (unsigned short*)d_ws;
    const size_t zElems = (size_t)bs * 8192;
    unsigned short* w0t = z + zElems;
    unsigned short* w1t = w0t + 64 * 128 * 64;
    unsigned short* w2t = w1t + 128 * 64 * 64;
    unsigned short* w3t = w2t + 128 * 64 * 64;
    unsigned short* xb  = w3t + 64 * 128 * 64;
    const size_t need1 = (zElems + 4ull * 524288) * sizeof(unsigned short);
    const size_t need2 = need1 + (size_t)bs * 4096 * sizeof(unsigned short);
    if (n_in < 7 || (bs & 15) || ws_size < need1) return;
    if (ws_size < need2) xb = (unsigned short*)d_out;  // dead until K2 writes

    transpose_cast_k<<<dim3(512), dim3(256), 0, stream>>>(w0, w0t, 64, 64, 128);
    transpose_cast_k<<<dim3(512), dim3(256), 0, stream>>>(w1, w1t, 128, 64, 64);
    transpose_cast_k<<<dim3(512), dim3(256), 0, stream>>>(w2, w2t, 128, 64, 64);
    transpose_cast_k<<<dim3(512), dim3(256), 0, stream>>>(w3, w3t, 64, 128, 64);
    cast_x_bf16<<<dim3(2048), dim3(256), 0, stream>>>(x, xb, bs * 4096 / 8);

    fusedR7<64, 128, true><<<dim3((bs / 16) * 8), dim3(256), 0, stream>>>(
        xb, w0t, w1t, b1, z, nullptr);
    fusedR7<128, 64, false><<<dim3((bs / 16) * 4), dim3(256), 0, stream>>>(
        z, w2t, w3t, b3, nullptr, out);
}

// Round 8
// 467.719 us; speedup vs baseline: 1.4095x; 1.1267x over previous
//
#include <hip/hip_runtime.h>

// Monarch block-MLP, round 8: operand-resident stile sweep.
// wg = 16 rows, 8 waves; the 8 waves jointly hold the whole input row-block
// in registers (wave w owns k-blocks w*8..w*8+7 of the current 64-kb group,
// 16 short8 = 64 VGPR). All stiles are processed inside the wg, so the
// streamed operand is read ONCE in K1 (f32 x, converted in the preload - the
// separate cast kernel is gone). K2 re-preloads per (stile, group) = x4 z
// re-read, but as 16 batched independent loads. Weights stream from L2.

typedef __attribute__((ext_vector_type(8))) short short8;
typedef __attribute__((ext_vector_type(4))) float floatx4;
typedef unsigned int uint;

#define MFMA32(a, b, c) __builtin_amdgcn_mfma_f32_16x16x32_bf16(a, b, c, 0, 0, 0)

__device__ __forceinline__ unsigned short f2bf(float f) {
    uint u = __float_as_uint(f);
    uint r = 0x7FFFu + ((u >> 16) & 1u);
    return (unsigned short)((u + r) >> 16);
}
__device__ __forceinline__ short8 ld8(const unsigned short* p) {
    return *reinterpret_cast<const short8*>(p);
}

// out[b][c][r] = bf16(in[b][r][c])
__global__ void transpose_cast_k(const float* __restrict__ in,
                                 unsigned short* __restrict__ out,
                                 int Bn, int R, int C) {
    int total = Bn * R * C;
    int stride = gridDim.x * blockDim.x;
    for (int idx = blockIdx.x * blockDim.x + threadIdx.x; idx < total; idx += stride) {
        int rc = R * C;
        int b = idx / rc;
        int rem = idx - b * rc;
        int c = rem / R;
        int r = rem - c * R;
        out[idx] = f2bf(in[(size_t)(b * R + r) * C + c]);
    }
}

// MFMA 16x16x32 bf16 layouts (m89-verified):
//   A: row = lane&15, k = (lane>>4)*8 + i ;  B: col = lane&15, same k
//   D: col = lane&15, row = (lane>>4)*4 + reg
template<int KB, int SN, bool ELU, bool F32IN>
__global__ __launch_bounds__(512, 2) void fusedR8(
    const void* __restrict__ xin,             // [bs][KB*64] f32 or bf16
    const unsigned short* __restrict__ wat,   // [KB][SN][64] bf16
    const unsigned short* __restrict__ wbt,   // [SN][64][KB] bf16
    const float* __restrict__ bias,           // [SN*64]
    unsigned short* __restrict__ ob,          // bf16 out (ELU)
    float* __restrict__ of)                   // f32 out
{
    constexpr int G  = KB / 64;       // 64-kb groups (1 or 2)
    constexpr int NS = SN / 16;       // stiles (8 or 4)
    constexpr int IW = KB * 64;
    constexpr int OW = SN * 64;
    constexpr int SROW = ELU ? 2048 : 4096;   // staging row bytes

    const int tid  = threadIdx.x;
    const int lane = tid & 63;
    const int wv   = tid >> 6;        // 0..7
    const int l15  = lane & 15;
    const int l4   = lane >> 4;       // 0..3
    const int r0   = blockIdx.x * 16;

    // 64 KB: y0s[16][17][72] (39 KB, XOR-swizzled) unioned with the
    // epilogue staging buffer (K1 32 KB bf16 / K2 64 KB f32).
    __shared__ __align__(16) unsigned short lds[32768];
    char* yb = (char*)lds;
    auto yoff = [&](int r, int s, int k) -> int {
        return (((r * 17 + s) * 72 + k) * 2) ^ ((r & 7) << 4);
    };
    auto soff = [&](int r, int b) -> int {
        return (r * SROW + b) ^ ((r & 7) << 4);
    };

    short8 xf[16];                    // wave's A-frags: 8 kb x 2 K-halves

    for (int ss = 0; ss < NS; ++ss) {
        floatx4 acc[2][4];
#pragma unroll
        for (int sl = 0; sl < 2; ++sl)
#pragma unroll
            for (int jq = 0; jq < 4; ++jq) acc[sl][jq] = (floatx4){0.f, 0.f, 0.f, 0.f};

        for (int g = 0; g < G; ++g) {
            // ---- preload this group's x A-frags (K1: only once) ----
            if (G > 1 || ss == 0) {
                if constexpr (F32IN) {
                    const float* xr = (const float*)xin + (size_t)(r0 + l15) * IW;
#pragma unroll
                    for (int t = 0; t < 8; ++t) {
                        const float* p = xr + (g * 64 + wv * 8 + t) * 64 + l4 * 8;
                        floatx4 u0 = *reinterpret_cast<const floatx4*>(p);
                        floatx4 u1 = *reinterpret_cast<const floatx4*>(p + 4);
                        floatx4 u2 = *reinterpret_cast<const floatx4*>(p + 32);
                        floatx4 u3 = *reinterpret_cast<const floatx4*>(p + 36);
                        short8 a, b;
#pragma unroll
                        for (int i = 0; i < 4; ++i) {
                            a[i] = (short)f2bf(u0[i]);  a[i + 4] = (short)f2bf(u1[i]);
                            b[i] = (short)f2bf(u2[i]);  b[i + 4] = (short)f2bf(u3[i]);
                        }
                        xf[t * 2] = a;  xf[t * 2 + 1] = b;
                    }
                } else {
                    const unsigned short* xr =
                        (const unsigned short*)xin + (size_t)(r0 + l15) * IW;
#pragma unroll
                    for (int t = 0; t < 8; ++t) {
                        const unsigned short* p = xr + (g * 64 + wv * 8 + t) * 64 + l4 * 8;
                        xf[t * 2]     = ld8(p);
                        xf[t * 2 + 1] = ld8(p + 32);
                    }
                }
            }

            // ---- stage A: y0[r][s][kb] for the wave's 8 kb ----
#pragma unroll
            for (int tp = 0; tp < 4; ++tp) {
                const int t0  = tp * 2;
                const int kb0 = g * 64 + wv * 8 + t0;
                const unsigned short* wp0 =
                    wat + ((size_t)kb0 * SN + ss * 16 + l15) * 64 + l4 * 8;
                const unsigned short* wp1 =
                    wat + ((size_t)(kb0 + 1) * SN + ss * 16 + l15) * 64 + l4 * 8;
                floatx4 d0 = (floatx4){0.f, 0.f, 0.f, 0.f};
                floatx4 d1 = (floatx4){0.f, 0.f, 0.f, 0.f};
                d0 = MFMA32(xf[t0 * 2],     ld8(wp0),      d0);
                d0 = MFMA32(xf[t0 * 2 + 1], ld8(wp0 + 32), d0);
                d1 = MFMA32(xf[t0 * 2 + 2], ld8(wp1),      d1);
                d1 = MFMA32(xf[t0 * 2 + 3], ld8(wp1 + 32), d1);
#pragma unroll
                for (int rg = 0; rg < 4; ++rg) {
                    uint pk = (uint)f2bf(d0[rg]) | ((uint)f2bf(d1[rg]) << 16);
                    *reinterpret_cast<uint*>(
                        yb + yoff(l4 * 4 + rg, l15, wv * 8 + t0)) = pk;
                }
            }
            __syncthreads();

            // ---- stage B: acc[sl][jq] += y0 @ wb, K=64 ----
#pragma unroll
            for (int sl = 0; sl < 2; ++sl) {
                const int s_local = wv * 2 + sl;
                const int sg = ss * 16 + s_local;
                short8 af0 = *reinterpret_cast<const short8*>(
                    yb + yoff(l15, s_local, l4 * 8));
                short8 af1 = *reinterpret_cast<const short8*>(
                    yb + yoff(l15, s_local, 32 + l4 * 8));
#pragma unroll
                for (int jq = 0; jq < 4; ++jq) {
                    const unsigned short* wp =
                        wbt + ((size_t)sg * 64 + jq * 16 + l15) * KB + g * 64 + l4 * 8;
                    acc[sl][jq] = MFMA32(af0, ld8(wp),      acc[sl][jq]);
                    acc[sl][jq] = MFMA32(af1, ld8(wp + 32), acc[sl][jq]);
                }
            }
            __syncthreads();
        }

        // ---- epilogue: bias (+ELU), LDS-staged, coalesced b128 stores ----
#pragma unroll
        for (int sl = 0; sl < 2; ++sl) {
            const int s_local = wv * 2 + sl;
            const int sg = ss * 16 + s_local;
#pragma unroll
            for (int jq = 0; jq < 4; ++jq) {
                const float bv = bias[sg * 64 + jq * 16 + l15];
                const int col = s_local * 64 + jq * 16 + l15;
#pragma unroll
                for (int rg = 0; rg < 4; ++rg) {
                    float v = acc[sl][jq][rg] + bv;
                    const int row = l4 * 4 + rg;
                    if constexpr (ELU) {
                        v = v > 0.f ? v : (__expf(v) - 1.f);
                        *reinterpret_cast<unsigned short*>(
                            yb + soff(row, col * 2)) = f2bf(v);
                    } else {
                        *reinterpret_cast<float*>(yb + soff(row, col * 4)) = v;
                    }
                }
            }
        }
        __syncthreads();
        if constexpr (ELU) {
#pragma unroll
            for (int p = 0; p < 4; ++p) {           // 32 KB out
                const int idx = p * 512 + tid;
                const int row = idx >> 7;           // 128 x 16B per row
                const int bo  = (idx & 127) * 16;
                short8 v = *reinterpret_cast<const short8*>(yb + soff(row, bo));
                *reinterpret_cast<short8*>(
                    (char*)(ob + (size_t)(r0 + row) * OW + ss * 1024) + bo) = v;
            }
        } else {
#pragma unroll
            for (int p = 0; p < 8; ++p) {           // 64 KB out
                const int idx = p * 512 + tid;
                const int row = idx >> 8;           // 256 x 16B per row
                const int bo  = (idx & 255) * 16;
                floatx4 v = *reinterpret_cast<const floatx4*>(yb + soff(row, bo));
                *reinterpret_cast<floatx4*>(
                    (char*)(of + (size_t)(r0 + row) * OW + ss * 1024) + bo) = v;
            }
        }
        if (ss + 1 < NS) __syncthreads();
    }
}

extern "C" void kernel_launch(void* const* d_in, const int* in_sizes, int n_in,
                              void* d_out, int out_size, void* d_ws, size_t ws_size,
                              hipStream_t stream) {
    const float* x  = (const float*)d_in[0];
    const float* w0 = (const float*)d_in[1];
    const float* w1 = (const float*)d_in[2];
    const float* b1 = (const float*)d_in[3];
    const float* w2 = (const float*)d_in[4];
    const float* w3 = (const float*)d_in[5];
    const float* b3 = (const float*)d_in[6];
    float* out = (float*)d_out;

    const int bs = in_sizes[0] / 4096;

    // ws (u16): z[bs*8192] | w0t | w1t | w2t | w3t
    unsigned short* z   = (unsigned short*)d_ws;
    const size_t zElems = (size_t)bs * 8192;
    unsigned short* w0t = z + zElems;
    unsigned short* w1t = w0t + 64 * 128 * 64;
    unsigned short* w2t = w1t + 128 * 64 * 64;
    unsigned short* w3t = w2t + 128 * 64 * 64;
    const size_t need = (zElems + 4ull * 524288) * sizeof(unsigned short);
    if (n_in < 7 || (bs & 15) || ws_size < need) return;

    transpose_cast_k<<<dim3(512), dim3(256), 0, stream>>>(w0, w0t, 64, 64, 128);
    transpose_cast_k<<<dim3(512), dim3(256), 0, stream>>>(w1, w1t, 128, 64, 64);
    transpose_cast_k<<<dim3(512), dim3(256), 0, stream>>>(w2, w2t, 128, 64, 64);
    transpose_cast_k<<<dim3(512), dim3(256), 0, stream>>>(w3, w3t, 64, 128, 64);

    // K1: x (f32) -> z (bf16, +b1, ELU); x read once per wg (reg-resident)
    fusedR8<64, 128, true, true><<<dim3(bs / 16), dim3(512), 0, stream>>>(
        x, w0t, w1t, b1, z, nullptr);
    // K2: z (bf16) -> out (f32, +b3)
    fusedR8<128, 64, false, false><<<dim3(bs / 16), dim3(512), 0, stream>>>(
        z, w2t, w3t, b3, nullptr, out);
}